// Round 1
// baseline (2054.676 us; speedup 1.0000x reference)
//
#include <hip/hip_runtime.h>
#include <math.h>

#define BN 16
#define CCH 384
#define GRP 8
#define CPG 48
#define HW4 4096
#define EPSV 1e-5f

static const long CN = (long)CCH * HW4;   // 1,572,864 per-batch [C,N] stride
static const long CC = (long)CCH * CCH;   // 147,456

#define TILE 64
#define KT 16
#define LDSP 68   // padded LDS leading dim (68*4B = 272B, 16B-aligned rows)

__device__ __forceinline__ float sigm(float x) { return 1.f / (1.f + expf(-x)); }

// EPI: 0=+bias store, 1=f-gate (sigmoid, rowsum->atomicAdd fsum, no store),
//      2=sigmoid store, 3=(+bias)*aux store (in-place gating),
//      4=alpha*(fsum[m]*prevM + acc) store (new_memory),
//      5=alpha*acc store, 6=acc + bias2[m] + x store (final+residual)
template<int EPI, bool BT>
__global__ __launch_bounds__(256) void gemm_k(
    const float* __restrict__ A, long sA,
    const float* __restrict__ Bm, long sB,
    float* Cm, long sC,
    int N, int K,
    const float* __restrict__ bias,
    const float* aux, long sAux,
    float* aux2,
    float alpha)
{
  __shared__ float As[KT][LDSP];
  __shared__ float Bs[KT][LDSP];
  const int b  = blockIdx.z;
  const float* Ab = A  + (long)b * sA;
  const float* Bb = Bm + (long)b * sB;
  const int m0 = blockIdx.y * TILE, n0 = blockIdx.x * TILE;
  const int tid = threadIdx.x;
  const int tx = tid & 15, ty = tid >> 4;
  const int lk = (tid & 3) * 4;     // k offset for transposed loads
  const int lr = tid >> 2;          // row 0..63

  float acc[4][4] = {{0.f}};

  for (int k0 = 0; k0 < K; k0 += KT) {
    float4 av = *(const float4*)(Ab + (long)(m0 + lr) * K + (k0 + lk));
    As[lk + 0][lr] = av.x; As[lk + 1][lr] = av.y;
    As[lk + 2][lr] = av.z; As[lk + 3][lr] = av.w;
    if (BT) {
      float4 bv = *(const float4*)(Bb + (long)(n0 + lr) * K + (k0 + lk));
      Bs[lk + 0][lr] = bv.x; Bs[lk + 1][lr] = bv.y;
      Bs[lk + 2][lr] = bv.z; Bs[lk + 3][lr] = bv.w;
    } else {
      float4 bv = *(const float4*)(Bb + (long)(k0 + (tid >> 4)) * N + (n0 + (tid & 15) * 4));
      *(float4*)&Bs[tid >> 4][(tid & 15) * 4] = bv;
    }
    __syncthreads();
#pragma unroll
    for (int kk = 0; kk < KT; ++kk) {
      float4 a  = *(const float4*)&As[kk][ty * 4];
      float4 bb = *(const float4*)&Bs[kk][tx * 4];
      acc[0][0] += a.x * bb.x; acc[0][1] += a.x * bb.y; acc[0][2] += a.x * bb.z; acc[0][3] += a.x * bb.w;
      acc[1][0] += a.y * bb.x; acc[1][1] += a.y * bb.y; acc[1][2] += a.y * bb.z; acc[1][3] += a.y * bb.w;
      acc[2][0] += a.z * bb.x; acc[2][1] += a.z * bb.y; acc[2][2] += a.z * bb.z; acc[2][3] += a.z * bb.w;
      acc[3][0] += a.w * bb.x; acc[3][1] += a.w * bb.y; acc[3][2] += a.w * bb.z; acc[3][3] += a.w * bb.w;
    }
    __syncthreads();
  }

  if (EPI == 1) {
    // f-gate: sigmoid, reduce row-sums across the 16 tx lanes, atomicAdd into fsum
#pragma unroll
    for (int i = 0; i < 4; i++) {
      const int m = m0 + ty * 4 + i;
      const float bsv = bias[m];
      float rs = sigm(acc[i][0] + bsv) + sigm(acc[i][1] + bsv) +
                 sigm(acc[i][2] + bsv) + sigm(acc[i][3] + bsv);
#pragma unroll
      for (int o = 8; o >= 1; o >>= 1) rs += __shfl_down(rs, o, 16);
      if (tx == 0) atomicAdd(&aux2[b * CCH + m], rs);
    }
  } else {
    float* Cb = Cm + (long)b * sC;
#pragma unroll
    for (int i = 0; i < 4; i++) {
      const int m = m0 + ty * 4 + i;
#pragma unroll
      for (int j = 0; j < 4; j++) {
        const int n = n0 + tx * 4 + j;
        float v = acc[i][j];
        if (EPI == 0) { v += bias[m]; }
        else if (EPI == 2) { v = sigm(v + bias[m]); }
        else if (EPI == 3) { v = (v + bias[m]) * aux[(long)b * sAux + (long)m * N + n]; }
        else if (EPI == 4) { v = alpha * (aux2[b * CCH + m] * aux[(long)b * sAux + (long)m * N + n] + v); }
        else if (EPI == 5) { v = alpha * v; }
        else if (EPI == 6) { v = v + aux2[b * CCH + m] + aux[(long)b * sAux + (long)m * N + n]; }
        Cb[(long)m * N + n] = v;
      }
    }
  }
}

// GroupNorm: one block per (b, g); two passes over the contiguous 48*4096 chunk.
__global__ __launch_bounds__(1024) void gn_kernel(const float* __restrict__ x,
                                                  const float* __restrict__ w,
                                                  const float* __restrict__ bsh,
                                                  float* __restrict__ xn)
{
  const int blk = blockIdx.x;
  const int b = blk >> 3, g = blk & 7;
  const long base = ((long)b * CCH + (long)g * CPG) * (long)HW4;
  const float4* xp = (const float4*)(x + base);
  float4* op = (float4*)(xn + base);
  const int n4 = CPG * HW4 / 4;   // 49152

  float s = 0.f, ss = 0.f;
  for (int i = threadIdx.x; i < n4; i += blockDim.x) {
    float4 v = xp[i];
    s  += v.x + v.y + v.z + v.w;
    ss += v.x * v.x + v.y * v.y + v.z * v.z + v.w * v.w;
  }
  __shared__ float red[2][16];
#pragma unroll
  for (int o = 32; o; o >>= 1) { s += __shfl_down(s, o); ss += __shfl_down(ss, o); }
  const int wid = threadIdx.x >> 6;
  if ((threadIdx.x & 63) == 0) { red[0][wid] = s; red[1][wid] = ss; }
  __syncthreads();
  if (threadIdx.x == 0) {
    float S = 0.f, SS = 0.f;
    const int nw = blockDim.x >> 6;
    for (int i = 0; i < nw; i++) { S += red[0][i]; SS += red[1][i]; }
    const float inv = 1.f / (float)(CPG * HW4);
    float mu = S * inv;
    float var = SS * inv - mu * mu;
    red[0][0] = mu;
    red[1][0] = rsqrtf(var + EPSV);
  }
  __syncthreads();
  const float mu = red[0][0], rstd = red[1][0];
  for (int i = threadIdx.x; i < n4; i += blockDim.x) {
    const int c = g * CPG + (i >> 10);        // 4096/4 = 1024 float4 per channel
    const float sw = w[c] * rstd;
    const float sb = bsh[c] - mu * sw;
    float4 v = xp[i];
    v.x = v.x * sw + sb; v.y = v.y * sw + sb;
    v.z = v.z * sw + sb; v.w = v.w * sw + sb;
    op[i] = v;
  }
}

// bias2[b,o] = scale * sum_j E[b,o,j]*bq[j] + bp[o]
__global__ __launch_bounds__(384) void bias2_kernel(const float* __restrict__ E,
                                                    const float* __restrict__ bq,
                                                    const float* __restrict__ bp,
                                                    float* __restrict__ bias2,
                                                    float scale)
{
  const int b = blockIdx.x;
  const int o = threadIdx.x;
  const float* Eb = E + (long)b * CC + (long)o * CCH;
  float s = 0.f;
  for (int j = 0; j < CCH; j++) s += Eb[j] * bq[j];
  bias2[b * CCH + o] = scale * s + bp[o];
}

extern "C" void kernel_launch(void* const* d_in, const int* in_sizes, int n_in,
                              void* d_out, int out_size, void* d_ws, size_t ws_size,
                              hipStream_t stream)
{
  const float* x     = (const float*)d_in[0];
  const float* prevM = (const float*)d_in[1];
  const float* nw    = (const float*)d_in[2];
  const float* nb    = (const float*)d_in[3];
  const float* Wq    = (const float*)d_in[4];
  const float* bq    = (const float*)d_in[5];
  const float* Wk    = (const float*)d_in[6];
  const float* bk    = (const float*)d_in[7];
  const float* Wv    = (const float*)d_in[8];
  const float* bv    = (const float*)d_in[9];
  const float* Wg    = (const float*)d_in[10];
  const float* bg    = (const float*)d_in[11];
  const float* Wp    = (const float*)d_in[12];
  const float* bp    = (const float*)d_in[13];

  float* out    = (float*)d_out;
  float* memOut = out + (long)BN * CCH * HW4;   // new_memory [B,C,C]

  float* ws    = (float*)d_ws;
  float* xn    = ws;                     // B*C*N
  float* ig    = xn + (long)BN * CN;     // i_gate, then overwritten in-place by k_gated
  float* vbuf  = ig + (long)BN * CN;     // v
  float* Eb    = vbuf + (long)BN * CN;   // B*C*C
  float* Fb    = Eb + (long)BN * CC;     // B*C*C
  float* fsum  = Fb + (long)BN * CC;     // B*C
  float* bias2 = fsum + (long)BN * CCH;  // B*C

  const float scale = 0.05103103630798288f;  // 1/sqrt(384)
  const float invN  = 1.f / (float)HW4;

  hipMemsetAsync(fsum, 0, (size_t)BN * CCH * sizeof(float), stream);

  // 1) GroupNorm
  gn_kernel<<<BN * GRP, 1024, 0, stream>>>(x, nw, nb, xn);

  dim3 blk(256);
  dim3 gBig(HW4 / TILE, CCH / TILE, BN);   // (64, 6, 16)
  dim3 gSq(CCH / TILE, CCH / TILE, BN);    // (6, 6, 16)

  // 2) f-gate: sigmoid(Wg[0:C] xn + bg[0:C]) -> row sums into fsum (no store)
  gemm_k<1, false><<<gBig, blk, 0, stream>>>(Wg, 0, xn, CN, nullptr, 0,
                                             HW4, CCH, bg, nullptr, 0, fsum, 0.f);
  // 3) i-gate: sigmoid(Wg[C:2C] xn + bg[C:2C]) -> ig
  gemm_k<2, false><<<gBig, blk, 0, stream>>>(Wg + CC, 0, xn, CN, ig, CN,
                                             HW4, CCH, bg + CCH, nullptr, 0, nullptr, 0.f);
  // 4) k_gated = (Wk xn + bk) * ig  (in-place on ig buffer)
  gemm_k<3, false><<<gBig, blk, 0, stream>>>(Wk, 0, xn, CN, ig, CN,
                                             HW4, CCH, bk, ig, CN, nullptr, 0.f);
  // 5) v = Wv xn + bv
  gemm_k<0, false><<<gBig, blk, 0, stream>>>(Wv, 0, xn, CN, vbuf, CN,
                                             HW4, CCH, bv, nullptr, 0, nullptr, 0.f);
  // 6) new_memory = (fsum/N)*prevM + (kg v^T)/N   -> d_out memory section
  gemm_k<4, true><<<gSq, blk, 0, stream>>>(ig, CN, vbuf, CN, memOut, CC,
                                           CCH, HW4, nullptr, prevM, CC, fsum, invN);
  // 7) E_b = Wp * M_b^T
  gemm_k<5, true><<<gSq, blk, 0, stream>>>(Wp, 0, memOut, CC, Eb, CC,
                                           CCH, CCH, nullptr, nullptr, 0, nullptr, 1.f);
  // 8) F_b = scale * E_b * Wq
  gemm_k<5, false><<<gSq, blk, 0, stream>>>(Eb, CC, Wq, 0, Fb, CC,
                                            CCH, CCH, nullptr, nullptr, 0, nullptr, scale);
  // 9) bias2 = scale * E_b bq + bp
  bias2_kernel<<<BN, 384, 0, stream>>>(Eb, bq, bp, bias2, scale);
  // 10) out = F_b xn + bias2 + x
  gemm_k<6, false><<<gBig, blk, 0, stream>>>(Fb, CC, xn, CN, out, CN,
                                             HW4, CCH, nullptr, x, CN, bias2, 0.f);
}

// Round 6
// 738.228 us; speedup vs baseline: 2.7833x; 2.7833x over previous
//
#include <hip/hip_runtime.h>
#include <math.h>

typedef __attribute__((ext_vector_type(8))) short short8;
typedef __attribute__((ext_vector_type(4))) float f32x4;

#define BN 16
#define CCH 384
#define GRP 8
#define CPG 48
#define HW4 4096
#define EPSV 1e-5f

static const long CN = (long)CCH * HW4;   // 1,572,864
static const long CC = (long)CCH * CCH;   // 147,456

__device__ __forceinline__ float sigm(float x) { return 1.f / (1.f + __expf(-x)); }
__device__ __forceinline__ ushort f2bf(float f) {
  unsigned u = __float_as_uint(f);
  unsigned r = (u + 0x7fffu + ((u >> 16) & 1u)) >> 16;
  return (ushort)r;
}
__device__ __forceinline__ float bf2f(ushort h) { return __uint_as_float(((unsigned)h) << 16); }

// ---------------- MFMA GEMM (NT: both operands [rows][K] row-major bf16) ----------------
// EPI 0: proj (stacked M=1536: f rows 0..383, interleaved i/k 384..1151, v 1152..1535)
// EPI 1: KV split-K partials (fp32 store)
// EPI 2: final, split-bf16 (A2/B2 = lo planes), out = acc + bias2[m] + x
template<int EPI, int BKT>
__global__ __launch_bounds__(256) void mgemm(
    const ushort* __restrict__ A, long sA, int ldA,
    const ushort* __restrict__ Bm, long sB, int ldB,
    int K,
    const float* __restrict__ bstack,
    float* fsum,
    ushort* kg, ushort* vv,
    const ushort* __restrict__ A2, const ushort* __restrict__ B2,
    float* outp, const float* __restrict__ bias2, const float* __restrict__ xres,
    float* part)
{
  constexpr int PITCH = BKT + 8;                 // 2-way LDS bank alias only (free)
  __shared__ ushort As[128 * PITCH];
  __shared__ ushort Bs[128 * PITCH];
  __shared__ ushort As2[(EPI == 2) ? 128 * PITCH : 8];
  __shared__ ushort Bs2[(EPI == 2) ? 128 * PITCH : 8];

  const int tid = threadIdx.x;
  const int lane = tid & 63;
  const int wid = tid >> 6;
  const int wm = wid >> 1, wn = wid & 1;         // 2x2 waves of 64x64
  const int m0 = blockIdx.y * 128, n0 = blockIdx.x * 128;

  int b = blockIdx.z, kbeg = 0, kend = K, s4 = 0;
  if (EPI == 1) { s4 = blockIdx.z & 3; b = blockIdx.z >> 2; int kc = K >> 2; kbeg = s4 * kc; kend = kbeg + kc; }

  const ushort* Ab = A + (long)b * sA;
  const ushort* Bb = Bm + (long)b * sB;

  f32x4 acc[4][4];
#pragma unroll
  for (int i = 0; i < 4; i++)
#pragma unroll
    for (int j = 0; j < 4; j++) acc[i][j] = (f32x4)0.f;

  const int r = tid >> 1, hh = tid & 1;
  const int colb = hh * (BKT / 2);

  for (int k0 = kbeg; k0 < kend; k0 += BKT) {
    {
      const ushort* sa = Ab + (long)(m0 + r) * ldA + k0 + colb;
      const ushort* sb = Bb + (long)(n0 + r) * ldB + k0 + colb;
      ushort* da = &As[r * PITCH + colb];
      ushort* db = &Bs[r * PITCH + colb];
#pragma unroll
      for (int c = 0; c < BKT / 16; ++c) {
        *(float4*)(da + 8 * c) = *(const float4*)(sa + 8 * c);
        *(float4*)(db + 8 * c) = *(const float4*)(sb + 8 * c);
      }
      if (EPI == 2) {
        const ushort* sa2 = A2 + (long)b * sA + (long)(m0 + r) * ldA + k0 + colb;
        const ushort* sb2 = B2 + (long)b * sB + (long)(n0 + r) * ldB + k0 + colb;
        ushort* da2 = &As2[r * PITCH + colb];
        ushort* db2 = &Bs2[r * PITCH + colb];
#pragma unroll
        for (int c = 0; c < BKT / 16; ++c) {
          *(float4*)(da2 + 8 * c) = *(const float4*)(sa2 + 8 * c);
          *(float4*)(db2 + 8 * c) = *(const float4*)(sb2 + 8 * c);
        }
      }
    }
    __syncthreads();
#pragma unroll
    for (int ks = 0; ks < BKT / 32; ++ks) {
      const int colf = ks * 32 + (lane >> 4) * 8;
      short8 af[4], bfr[4];
#pragma unroll
      for (int mf = 0; mf < 4; ++mf)
        af[mf] = *(const short8*)&As[(wm * 64 + mf * 16 + (lane & 15)) * PITCH + colf];
#pragma unroll
      for (int nf = 0; nf < 4; ++nf)
        bfr[nf] = *(const short8*)&Bs[(wn * 64 + nf * 16 + (lane & 15)) * PITCH + colf];
      if (EPI == 2) {
        short8 af2[4], bfr2[4];
#pragma unroll
        for (int mf = 0; mf < 4; ++mf)
          af2[mf] = *(const short8*)&As2[(wm * 64 + mf * 16 + (lane & 15)) * PITCH + colf];
#pragma unroll
        for (int nf = 0; nf < 4; ++nf)
          bfr2[nf] = *(const short8*)&Bs2[(wn * 64 + nf * 16 + (lane & 15)) * PITCH + colf];
#pragma unroll
        for (int mf = 0; mf < 4; ++mf)
#pragma unroll
          for (int nf = 0; nf < 4; ++nf) {
            acc[mf][nf] = __builtin_amdgcn_mfma_f32_16x16x32_bf16(af[mf], bfr[nf], acc[mf][nf], 0, 0, 0);
            acc[mf][nf] = __builtin_amdgcn_mfma_f32_16x16x32_bf16(af[mf], bfr2[nf], acc[mf][nf], 0, 0, 0);
            acc[mf][nf] = __builtin_amdgcn_mfma_f32_16x16x32_bf16(af2[mf], bfr[nf], acc[mf][nf], 0, 0, 0);
          }
      } else {
#pragma unroll
        for (int mf = 0; mf < 4; ++mf)
#pragma unroll
          for (int nf = 0; nf < 4; ++nf)
            acc[mf][nf] = __builtin_amdgcn_mfma_f32_16x16x32_bf16(af[mf], bfr[nf], acc[mf][nf], 0, 0, 0);
      }
    }
    __syncthreads();
  }

  const int g4 = lane >> 4;
  const int lc = lane & 15;
  if (EPI == 0) {
    if (m0 < 384) {                    // f-gate: sigmoid + rowsum -> fsum (no store)
#pragma unroll
      for (int mf = 0; mf < 4; ++mf) {
        const int base = m0 + wm * 64 + mf * 16 + 4 * g4;
#pragma unroll
        for (int reg = 0; reg < 4; ++reg) {
          const float bs = bstack[base + reg];
          float ssum = 0.f;
#pragma unroll
          for (int nf = 0; nf < 4; ++nf) ssum += sigm(acc[mf][nf][reg] + bs);
#pragma unroll
          for (int o = 8; o >= 1; o >>= 1) ssum += __shfl_down(ssum, o, 16);
          if (lc == 0) atomicAdd(&fsum[b * CCH + base + reg], ssum);
        }
      }
    } else if (m0 < 1152) {            // interleaved i/k: kg = (k+bk)*sigmoid(i+bi)
#pragma unroll
      for (int mf = 0; mf < 4; ++mf) {
        const int base = m0 + wm * 64 + mf * 16 + 4 * g4;
        const int cp = (base - 384) >> 1;
        const float b0 = bstack[base], b1 = bstack[base + 1];
        const float b2v = bstack[base + 2], b3 = bstack[base + 3];
#pragma unroll
        for (int nf = 0; nf < 4; ++nf) {
          const int n = n0 + wn * 64 + nf * 16 + lc;
          float i0 = sigm(acc[mf][nf][0] + b0);
          kg[((long)b * CCH + cp) * HW4 + n] = f2bf((acc[mf][nf][1] + b1) * i0);
          float i1 = sigm(acc[mf][nf][2] + b2v);
          kg[((long)b * CCH + cp + 1) * HW4 + n] = f2bf((acc[mf][nf][3] + b3) * i1);
        }
      }
    } else {                           // v
#pragma unroll
      for (int mf = 0; mf < 4; ++mf) {
        const int base = m0 + wm * 64 + mf * 16 + 4 * g4;
#pragma unroll
        for (int reg = 0; reg < 4; ++reg) {
          const int c = base - 1152 + reg;
          const float bs = bstack[base + reg];
#pragma unroll
          for (int nf = 0; nf < 4; ++nf) {
            const int n = n0 + wn * 64 + nf * 16 + lc;
            vv[((long)b * CCH + c) * HW4 + n] = f2bf(acc[mf][nf][reg] + bs);
          }
        }
      }
    }
  } else if (EPI == 1) {
    float* pb = part + (long)(s4 * 16 + b) * CC;
#pragma unroll
    for (int mf = 0; mf < 4; ++mf) {
      const int base = m0 + wm * 64 + mf * 16 + 4 * g4;
#pragma unroll
      for (int reg = 0; reg < 4; ++reg)
#pragma unroll
        for (int nf = 0; nf < 4; ++nf) {
          const int n = n0 + wn * 64 + nf * 16 + lc;
          pb[(long)(base + reg) * CCH + n] = acc[mf][nf][reg];
        }
    }
  } else {                             // final: + bias2 + residual x
#pragma unroll
    for (int mf = 0; mf < 4; ++mf) {
      const int base = m0 + wm * 64 + mf * 16 + 4 * g4;
#pragma unroll
      for (int reg = 0; reg < 4; ++reg) {
        const float b2v = bias2[b * CCH + base + reg];
#pragma unroll
        for (int nf = 0; nf < 4; ++nf) {
          const int n = n0 + wn * 64 + nf * 16 + lc;
          const long idx = ((long)b * CCH + base + reg) * HW4 + n;
          outp[idx] = acc[mf][nf][reg] + b2v + xres[idx];
        }
      }
    }
  }
}

// ---------------- GroupNorm stats ----------------
__global__ __launch_bounds__(1024) void gn_stats(const float* __restrict__ x, float* __restrict__ stats)
{
  const int blk = blockIdx.x;
  const int b = blk >> 3, g = blk & 7;
  const long base = ((long)b * CCH + (long)g * CPG) * (long)HW4;
  const float4* xp = (const float4*)(x + base);
  const int n4 = CPG * HW4 / 4;
  float s = 0.f, ss = 0.f;
  for (int i = threadIdx.x; i < n4; i += 1024) {
    float4 v = xp[i];
    s += v.x + v.y + v.z + v.w;
    ss += v.x * v.x + v.y * v.y + v.z * v.z + v.w * v.w;
  }
  __shared__ float red[2][16];
#pragma unroll
  for (int o = 32; o; o >>= 1) { s += __shfl_down(s, o); ss += __shfl_down(ss, o); }
  const int wv = threadIdx.x >> 6;
  if ((threadIdx.x & 63) == 0) { red[0][wv] = s; red[1][wv] = ss; }
  __syncthreads();
  if (threadIdx.x == 0) {
    float S = 0.f, SS = 0.f;
    for (int i = 0; i < 16; i++) { S += red[0][i]; SS += red[1][i]; }
    const float inv = 1.f / (float)(CPG * HW4);
    float mu = S * inv;
    float var = SS * inv - mu * mu;
    stats[blk * 2] = mu;
    stats[blk * 2 + 1] = rsqrtf(var + EPSV);
  }
}

// ---------------- GroupNorm apply + transpose + bf16 hi/lo split ----------------
__global__ __launch_bounds__(256) void gn_apply(const float* __restrict__ x,
    const float* __restrict__ w, const float* __restrict__ bb,
    const float* __restrict__ stats, ushort* __restrict__ hi, ushort* __restrict__ lo)
{
  const int b = blockIdx.z, n0 = blockIdx.x * 64, c0 = blockIdx.y * 64;
  __shared__ float tile[64][65];
  __shared__ float sw_s[64], sb_s[64];
  const int t = threadIdx.x;
  if (t < 64) {
    int c = c0 + t; int g = c / CPG;
    float mu = stats[(b * 8 + g) * 2], rs = stats[(b * 8 + g) * 2 + 1];
    float sw = w[c] * rs;
    sw_s[t] = sw; sb_s[t] = bb[c] - mu * sw;
  }
  __syncthreads();
  {
    const int rr = t >> 2, nc = (t & 3) * 16;
    const float* xp = x + ((long)(b * CCH + c0 + rr)) * HW4 + n0 + nc;
    const float sw = sw_s[rr], sb = sb_s[rr];
#pragma unroll
    for (int i = 0; i < 4; i++) {
      float4 v = ((const float4*)xp)[i];
      tile[rr][nc + 4 * i + 0] = v.x * sw + sb;
      tile[rr][nc + 4 * i + 1] = v.y * sw + sb;
      tile[rr][nc + 4 * i + 2] = v.z * sw + sb;
      tile[rr][nc + 4 * i + 3] = v.w * sw + sb;
    }
  }
  __syncthreads();
  {
    const int n = t >> 2, cc = (t & 3) * 16;
    union F4 { ushort u[8]; float4 v; } ph[2], pl[2];
#pragma unroll
    for (int j = 0; j < 16; j++) {
      float f = tile[cc + j][n];
      ushort h = f2bf(f);
      ph[j >> 3].u[j & 7] = h;
      pl[j >> 3].u[j & 7] = f2bf(f - bf2f(h));
    }
    const long idx = ((long)b * HW4 + n0 + n) * CCH + c0 + cc;
    *(float4*)(hi + idx) = ph[0].v;
    *(float4*)(hi + idx + 8) = ph[1].v;
    *(float4*)(lo + idx) = pl[0].v;
    *(float4*)(lo + idx + 8) = pl[1].v;
  }
}

// ---------------- weight stack prep ----------------
__global__ __launch_bounds__(256) void prep_w(const float* __restrict__ Wg, const float* __restrict__ Wk,
    const float* __restrict__ Wv, const float* __restrict__ bg, const float* __restrict__ bk,
    const float* __restrict__ bv, ushort* __restrict__ Wstack, float* __restrict__ bstack)
{
  const int idx = blockIdx.x * 256 + threadIdx.x;   // < 1536*384
  const int rr = idx / CCH, c = idx - rr * CCH;
  float val, bval;
  if (rr < 384) { val = Wg[rr * CCH + c]; bval = bg[rr]; }
  else if (rr < 1152) {
    int q = rr - 384; int ch = q >> 1;
    if (!(q & 1)) { val = Wg[(384 + ch) * CCH + c]; bval = bg[384 + ch]; }
    else          { val = Wk[ch * CCH + c];         bval = bk[ch]; }
  } else { val = Wv[(rr - 1152) * CCH + c]; bval = bv[rr - 1152]; }
  Wstack[idx] = f2bf(val);
  if (c == 0) bstack[rr] = bval;
}

// ---------------- KV finish: new_memory = (fsum/N)*prevM + know/N ----------------
__global__ __launch_bounds__(256) void kv_finish(const float* __restrict__ part,
    const float* __restrict__ fsum, const float* __restrict__ prevM, float* __restrict__ memOut)
{
  const int b = blockIdx.y;
  const long idx = (long)blockIdx.x * 256 + threadIdx.x;  // < 147456
  const long gidx = (long)b * CC + idx;
  const int c = (int)(idx / CCH);
  const long ss = (long)16 * CC;
  float know = part[gidx] + part[gidx + ss] + part[gidx + 2 * ss] + part[gidx + 3 * ss];
  const float inv = 1.f / (float)HW4;
  memOut[gidx] = fsum[b * CCH + c] * inv * prevM[gidx] + know * inv;
}

// ---------------- F -> bf16 hi/lo ----------------
__global__ __launch_bounds__(256) void fconv(const float* __restrict__ F,
    ushort* __restrict__ hi, ushort* __restrict__ lo)
{
  const long i = (long)blockIdx.x * 256 + threadIdx.x;
  float f = F[i];
  ushort h = f2bf(f);
  hi[i] = h;
  lo[i] = f2bf(f - bf2f(h));
}

// ---------------- small fp32 GEMM (E, F chain) ----------------
#define TILE 64
#define KT 16
#define LDSP 68
template<bool BT>
__global__ __launch_bounds__(256) void gemm_f32(
    const float* __restrict__ A, long sA,
    const float* __restrict__ Bm, long sB,
    float* Cm, long sC, int N, int K, float alpha)
{
  __shared__ float As[KT][LDSP];
  __shared__ float Bs[KT][LDSP];
  const int b = blockIdx.z;
  const float* Ab = A + (long)b * sA;
  const float* Bb = Bm + (long)b * sB;
  const int m0 = blockIdx.y * TILE, n0 = blockIdx.x * TILE;
  const int tid = threadIdx.x;
  const int tx = tid & 15, ty = tid >> 4;
  const int lk = (tid & 3) * 4;
  const int lr = tid >> 2;
  float acc[4][4] = {{0.f}};
  for (int k0 = 0; k0 < K; k0 += KT) {
    float4 av = *(const float4*)(Ab + (long)(m0 + lr) * K + (k0 + lk));
    As[lk + 0][lr] = av.x; As[lk + 1][lr] = av.y;
    As[lk + 2][lr] = av.z; As[lk + 3][lr] = av.w;
    if (BT) {
      float4 bv = *(const float4*)(Bb + (long)(n0 + lr) * K + (k0 + lk));
      Bs[lk + 0][lr] = bv.x; Bs[lk + 1][lr] = bv.y;
      Bs[lk + 2][lr] = bv.z; Bs[lk + 3][lr] = bv.w;
    } else {
      float4 bv = *(const float4*)(Bb + (long)(k0 + (tid >> 4)) * N + (n0 + (tid & 15) * 4));
      *(float4*)&Bs[tid >> 4][(tid & 15) * 4] = bv;
    }
    __syncthreads();
#pragma unroll
    for (int kk = 0; kk < KT; ++kk) {
      float4 a = *(const float4*)&As[kk][ty * 4];
      float4 bb = *(const float4*)&Bs[kk][tx * 4];
      acc[0][0] += a.x * bb.x; acc[0][1] += a.x * bb.y; acc[0][2] += a.x * bb.z; acc[0][3] += a.x * bb.w;
      acc[1][0] += a.y * bb.x; acc[1][1] += a.y * bb.y; acc[1][2] += a.y * bb.z; acc[1][3] += a.y * bb.w;
      acc[2][0] += a.z * bb.x; acc[2][1] += a.z * bb.y; acc[2][2] += a.z * bb.z; acc[2][3] += a.z * bb.w;
      acc[3][0] += a.w * bb.x; acc[3][1] += a.w * bb.y; acc[3][2] += a.w * bb.z; acc[3][3] += a.w * bb.w;
    }
    __syncthreads();
  }
  float* Cb = Cm + (long)b * sC;
#pragma unroll
  for (int i = 0; i < 4; i++) {
    const int m = m0 + ty * 4 + i;
#pragma unroll
    for (int j = 0; j < 4; j++) {
      const int n = n0 + tx * 4 + j;
      Cb[(long)m * N + n] = alpha * acc[i][j];
    }
  }
}

// bias2[b,o] = scale * sum_j E[b,o,j]*bq[j] + bp[o]
__global__ __launch_bounds__(384) void bias2_kernel(const float* __restrict__ E,
    const float* __restrict__ bq, const float* __restrict__ bp,
    float* __restrict__ bias2, float scale)
{
  const int b = blockIdx.x;
  const int o = threadIdx.x;
  const float* Eb = E + (long)b * CC + (long)o * CCH;
  float s = 0.f;
  for (int j = 0; j < CCH; j++) s += Eb[j] * bq[j];
  bias2[b * CCH + o] = scale * s + bp[o];
}

extern "C" void kernel_launch(void* const* d_in, const int* in_sizes, int n_in,
                              void* d_out, int out_size, void* d_ws, size_t ws_size,
                              hipStream_t stream)
{
  const float* x     = (const float*)d_in[0];
  const float* prevM = (const float*)d_in[1];
  const float* nw    = (const float*)d_in[2];
  const float* nb    = (const float*)d_in[3];
  const float* Wq    = (const float*)d_in[4];
  const float* bq    = (const float*)d_in[5];
  const float* Wk    = (const float*)d_in[6];
  const float* bk    = (const float*)d_in[7];
  const float* Wv    = (const float*)d_in[8];
  const float* bv    = (const float*)d_in[9];
  const float* Wg    = (const float*)d_in[10];
  const float* bg    = (const float*)d_in[11];
  const float* Wp    = (const float*)d_in[12];
  const float* bp    = (const float*)d_in[13];

  float* out    = (float*)d_out;
  float* memOut = out + (long)BN * CN;            // new_memory [B,C,C]

  // workspace carve-up (all 16B aligned)
  ushort* xnThi = (ushort*)d_ws;                  // B*N*C bf16
  ushort* xnTlo = xnThi + (long)BN * CN;
  ushort* kg    = xnTlo + (long)BN * CN;          // [B][C][N] bf16
  ushort* vbuf  = kg + (long)BN * CN;
  ushort* Wstk  = vbuf + (long)BN * CN;           // 1536*384 bf16
  float*  bstk  = (float*)(Wstk + (long)1536 * CCH);
  float*  fsum  = bstk + 1536;                    // B*C
  float*  bias2 = fsum + BN * CCH;                // B*C
  float*  stats = bias2 + BN * CCH;               // B*8*2
  float*  part  = stats + BN * GRP * 2;           // 4*B*C*C fp32
  float*  Eb    = part + (long)4 * BN * CC;       // B*C*C fp32
  float*  Fb    = Eb + (long)BN * CC;
  ushort* Fhi   = (ushort*)(Fb + (long)BN * CC);
  ushort* Flo   = Fhi + (long)BN * CC;

  const float scale = 0.05103103630798288f;       // 1/sqrt(384)

  hipMemsetAsync(fsum, 0, (size_t)BN * CCH * sizeof(float), stream);

  // 1) weight stack (bf16) + stacked bias
  prep_w<<<(1536 * CCH) / 256, 256, 0, stream>>>(Wg, Wk, Wv, bg, bk, bv, Wstk, bstk);
  // 2) groupnorm stats, then apply+transpose+bf16-split
  gn_stats<<<BN * GRP, 1024, 0, stream>>>(x, stats);
  gn_apply<<<dim3(HW4 / 64, CCH / 64, BN), 256, 0, stream>>>(x, nw, nb, stats, xnThi, xnTlo);
  // 3) fused projections (f rowsum, kg, v)
  mgemm<0, 64><<<dim3(HW4 / 128, 1536 / 128, BN), 256, 0, stream>>>(
      Wstk, 0, CCH, xnThi, CN, CCH, CCH,
      bstk, fsum, kg, vbuf, nullptr, nullptr, nullptr, nullptr, nullptr, nullptr);
  // 4) KV split-K partials
  mgemm<1, 64><<<dim3(CCH / 128, CCH / 128, BN * 4), 256, 0, stream>>>(
      kg, CN, HW4, vbuf, CN, HW4, HW4,
      nullptr, nullptr, nullptr, nullptr, nullptr, nullptr, nullptr, nullptr, nullptr, part);
  // 5) finish new_memory
  kv_finish<<<dim3(CC / 256, BN), 256, 0, stream>>>(part, fsum, prevM, memOut);
  // 6) E = Wp * M^T ; F = scale * E * Wq  (fp32 chain for accuracy)
  gemm_f32<true><<<dim3(CCH / TILE, CCH / TILE, BN), 256, 0, stream>>>(Wp, 0, memOut, CC, Eb, CC, CCH, CCH, 1.f);
  gemm_f32<false><<<dim3(CCH / TILE, CCH / TILE, BN), 256, 0, stream>>>(Eb, CC, Wq, 0, Fb, CC, CCH, CCH, scale);
  // 7) bias2 = scale*E*bq + bp ; F -> bf16 hi/lo
  bias2_kernel<<<BN, 384, 0, stream>>>(Eb, bq, bp, bias2, scale);
  fconv<<<(int)((long)BN * CC / 256), 256, 0, stream>>>(Fb, Fhi, Flo);
  // 8) out = F*xn + bias2 + x  (split-bf16, 3-product)
  mgemm<2, 32><<<dim3(HW4 / 128, CCH / 128, BN), 256, 0, stream>>>(
      Fhi, CC, CCH, xnThi, CN, CCH, CCH,
      nullptr, nullptr, nullptr, nullptr, Flo, xnTlo, out, bias2, x, nullptr);
}